// Round 8
// baseline (586.996 us; speedup 1.0000x reference)
//
#include <hip/hip_runtime.h>
#include <math.h>
#include <string.h>

#define NPTS 200000
#define KNBR 16
#define CDIM 32
#define NITEM (NPTS * KNBR)               // 3,200,000
#define TEMP 0.1f
#define WEIGHT 0.1f
#define EPSV 1e-8f

#define PART_BLOCKS 2048                  // 1024 per dim-group
#define CHUNK (NITEM / 1024)              // 3125 items per partial block
#define CONVBLK (NPTS * CDIM / 8 / 256)   // 3125
#define SM_BLOCKS (NITEM / 256)           // 12500

// ---- workspace layout (256-aligned) ----
#define TBLA_OFF 256
#define TBLB_OFF (TBLA_OFF + NPTS * 16)           // 3,200,256
#define D2A_OFF  (TBLB_OFF + NPTS * 16)           // 6,400,512
#define D2B_OFF  (D2A_OFF + NITEM * 2)            // 12,800,512
#define WS_NEEDED ((size_t)(D2B_OFF + NITEM * 2)) // 19,200,512

typedef float v2f __attribute__((ext_vector_type(2)));

static __device__ __forceinline__ unsigned short f32_to_f16b(float x) {
    _Float16 h = (_Float16)x;
    unsigned short u;
    __builtin_memcpy(&u, &h, 2);
    return u;
}
static __device__ __forceinline__ float f16b_to_f32(unsigned short u) {
    _Float16 h;
    __builtin_memcpy(&h, &u, 2);
    return (float)h;
}

// ---------- K1: f32 features -> two fp8 half-tables (16B rows each) --------
__global__ __launch_bounds__(256) void to_fp8_split(const float* __restrict__ f,
                                                    unsigned char* __restrict__ A,
                                                    unsigned char* __restrict__ B) {
    const int i = blockIdx.x * 256 + threadIdx.x;   // 800000 threads, 8 floats each
    const float4 a = ((const float4*)f)[2 * i];
    const float4 b = ((const float4*)f)[2 * i + 1];
    int w0 = 0, w1 = 0;
    w0 = __builtin_amdgcn_cvt_pk_fp8_f32(a.x, a.y, w0, false);
    w0 = __builtin_amdgcn_cvt_pk_fp8_f32(a.z, a.w, w0, true);
    w1 = __builtin_amdgcn_cvt_pk_fp8_f32(b.x, b.y, w1, false);
    w1 = __builtin_amdgcn_cvt_pk_fp8_f32(b.z, b.w, w1, true);
    const int fbase = i * 8;
    const int p = fbase >> 5;                       // point
    unsigned char* dst = ((fbase >> 4) & 1) ? B : A;
    *(uint2*)(dst + (size_t)p * 16 + (fbase & 15)) =
        make_uint2((unsigned)w0, (unsigned)w1);     // (fbase&15) in {0,8}
}

// ---------- K2: per-item partial d^2 over 16 dims, XCD-grouped -------------
// (blockIdx&7)<4 -> XCDs 0-3 -> tblA (dims 0-15); else tblB (dims 16-31).
// Each XCD's random working set = 3.2MB half-table -> L2-resident -> hits.
__global__ __launch_bounds__(256) void partial_d2(
    const unsigned char* __restrict__ tblA,
    const unsigned char* __restrict__ tblB,
    const int* __restrict__ nbr,
    unsigned short* __restrict__ d2A,
    unsigned short* __restrict__ d2B) {
    const int b = blockIdx.x;
    const int grp = (b >> 2) & 1;                  // 0: xcd 0-3, 1: xcd 4-7
    const int r = (b >> 3) * 4 + (b & 3);          // rank within group, 0..1023
    const unsigned char* __restrict__ tbl = grp ? tblB : tblA;
    unsigned short* __restrict__ out = grp ? d2B : d2A;
    const int i0 = r * CHUNK;

    for (int t = threadIdx.x; t < CHUNK; t += 256) {
        const int i = i0 + t;
        const int idx = nbr[i];                    // coalesced
        const int p = i >> 4;                      // 16 consecutive lanes share p
        const uint4 nv = *(const uint4*)(tbl + (size_t)idx * 16);  // L2 hit
        const uint4 cv = *(const uint4*)(tbl + (size_t)p * 16);    // broadcast
        const unsigned* pn = (const unsigned*)&nv;
        const unsigned* pc = (const unsigned*)&cv;
        float d2 = 0.f;
        #pragma unroll
        for (int q = 0; q < 4; ++q) {
            v2f nl = __builtin_amdgcn_cvt_pk_f32_fp8((int)pn[q], false);
            v2f nh = __builtin_amdgcn_cvt_pk_f32_fp8((int)pn[q], true);
            v2f cl = __builtin_amdgcn_cvt_pk_f32_fp8((int)pc[q], false);
            v2f ch = __builtin_amdgcn_cvt_pk_f32_fp8((int)pc[q], true);
            float a0 = cl.x - nl.x, a1 = cl.y - nl.y;
            float a2 = ch.x - nh.x, a3 = ch.y - nh.y;
            d2 += a0 * a0 + a1 * a1 + a2 * a2 + a3 * a3;
        }
        out[i] = f32_to_f16b(d2);                  // coalesced 2B stream
    }
}

// ---------- K3: combine halves, exact R4 softmax/mask, fused finalize ------
__global__ __launch_bounds__(256) void softmax_fin(
    const unsigned short* __restrict__ d2A,
    const unsigned short* __restrict__ d2B,
    const int* __restrict__ labels,
    const int* __restrict__ nbr,
    float* __restrict__ ws, int* __restrict__ ctr,
    float* __restrict__ out, int nblocks) {
    const int tid = threadIdx.x;
    const int i = blockIdx.x * 256 + tid;          // item, grid covers NITEM exactly
    const int lane = tid & 63;
    const int p = i >> 4;

    const int idx = nbr[i];                        // coalesced
    const int labn = labels[idx];                  // random, 800KB L2-resident
    const int labc = labels[p];                    // broadcast across 16 lanes
    const float d2 = f16b_to_f32(d2A[i]) + f16b_to_f32(d2B[i]);
    const float d = sqrtf(d2 + EPSV);

    float mn = d;                                  // min over the point's 16 lanes
    mn = fminf(mn, __shfl_xor(mn, 1));
    mn = fminf(mn, __shfl_xor(mn, 2));
    mn = fminf(mn, __shfl_xor(mn, 4));
    mn = fminf(mn, __shfl_xor(mn, 8));
    const float e = expf((mn - d) * (1.0f / TEMP));
    const bool pos = (labn == labc);

    float pos_s = pos ? e : 0.f;
    float neg_s = e;
    float cnt_s = pos ? 1.f : 0.f;
    #pragma unroll
    for (int off = 1; off <= 8; off <<= 1) {
        pos_s += __shfl_xor(pos_s, off);
        neg_s += __shfl_xor(neg_s, off);
        cnt_s += __shfl_xor(cnt_s, off);
    }

    float l = 0.f, v = 0.f;
    if ((lane & 15) == 0) {
        const int icnt = (int)(cnt_s + 0.5f);
        if (icnt > 0 && icnt < KNBR) {
            l = -logf(pos_s / neg_s + EPSV);
            v = 1.f;
        }
    }
    l += __shfl_xor(l, 16); v += __shfl_xor(v, 16);
    l += __shfl_xor(l, 32); v += __shfl_xor(v, 32);

    __shared__ float sl, sv;
    __shared__ int isLast;
    if (tid == 0) { sl = 0.f; sv = 0.f; }
    __syncthreads();
    if (lane == 0) { atomicAdd(&sl, l); atomicAdd(&sv, v); }
    __syncthreads();
    if (tid == 0) {
        atomicAdd(&ws[0], sl);
        atomicAdd(&ws[1], sv);
        __threadfence();
        isLast = (atomicAdd(ctr, 1) == nblocks - 1);
    }
    __syncthreads();
    if (isLast && tid == 0) {
        const float S = atomicAdd(&ws[0], 0.f);    // coherent cross-XCD reads
        const float C = atomicAdd(&ws[1], 0.f);
        out[0] = S / fmaxf(C, 1.f) * WEIGHT;
    }
}

// ---------------- fp32 direct fallback (tiny ws) ---------------------------
__global__ __launch_bounds__(256) void contrast_fp32(
    const float* __restrict__ features,
    const int* __restrict__ labels,
    const int* __restrict__ nbr,
    float* __restrict__ ws) {
    const int lane = threadIdx.x & 63;
    const int wave = threadIdx.x >> 6;
    const int p0 = blockIdx.x * 16 + wave * 4;
    const int m = lane >> 3;
    const int c = lane & 7;
    const int idx_l = nbr[p0 * KNBR + lane];
    const int labn_l = labels[idx_l];
    const int labc_l = labels[p0 + (lane >> 4)];
    float4 cen[4];
    #pragma unroll
    for (int pt = 0; pt < 4; ++pt)
        cen[pt] = *(const float4*)(features + (size_t)(p0 + pt) * CDIM + c * 4);
    int ridx[8];
    #pragma unroll
    for (int j = 0; j < 8; ++j) ridx[j] = __shfl(idx_l, 8 * j + m);
    float4 v[8];
    #pragma unroll
    for (int j = 0; j < 8; ++j)
        v[j] = *(const float4*)(features + (size_t)ridx[j] * CDIM + c * 4);
    float dj[8];
    #pragma unroll
    for (int j = 0; j < 8; ++j) {
        float4 ce = cen[j >> 1];
        float dx = ce.x - v[j].x, dy = ce.y - v[j].y;
        float dz = ce.z - v[j].z, dw = ce.w - v[j].w;
        float d2 = dx * dx + dy * dy + dz * dz + dw * dw;
        d2 += __shfl_xor(d2, 1);
        d2 += __shfl_xor(d2, 2);
        d2 += __shfl_xor(d2, 4);
        dj[j] = sqrtf(d2 + EPSV);
    }
    float loss_acc = 0.f, valid_acc = 0.f;
    #pragma unroll
    for (int pt = 0; pt < 4; ++pt) {
        float a = dj[2 * pt], b = dj[2 * pt + 1];
        float mn = fminf(a, b);
        mn = fminf(mn, __shfl_xor(mn, 8));
        mn = fminf(mn, __shfl_xor(mn, 16));
        mn = fminf(mn, __shfl_xor(mn, 32));
        const float ea = expf((mn - a) / TEMP);
        const float eb = expf((mn - b) / TEMP);
        const int la = __shfl(labn_l, 16 * pt + m);
        const int lb = __shfl(labn_l, 16 * pt + 8 + m);
        const int lc = __shfl(labc_l, 16 * pt);
        float pos_s = (la == lc ? ea : 0.f) + (lb == lc ? eb : 0.f);
        float neg_s = ea + eb;
        float cnt_s = (la == lc ? 1.f : 0.f) + (lb == lc ? 1.f : 0.f);
        #pragma unroll
        for (int off = 8; off <= 32; off <<= 1) {
            pos_s += __shfl_xor(pos_s, off);
            neg_s += __shfl_xor(neg_s, off);
            cnt_s += __shfl_xor(cnt_s, off);
        }
        if (lane == pt) {
            const int icnt = (int)(cnt_s + 0.5f);
            if (icnt > 0 && icnt < KNBR) {
                loss_acc += -logf(pos_s / neg_s + EPSV);
                valid_acc += 1.f;
            }
        }
    }
    __shared__ float s_loss, s_cnt;
    if (threadIdx.x == 0) { s_loss = 0.f; s_cnt = 0.f; }
    __syncthreads();
    if (lane < 4) { atomicAdd(&s_loss, loss_acc); atomicAdd(&s_cnt, valid_acc); }
    __syncthreads();
    if (threadIdx.x == 0) { atomicAdd(&ws[0], s_loss); atomicAdd(&ws[1], s_cnt); }
}

__global__ void contrast_finalize(const float* __restrict__ ws,
                                  float* __restrict__ out) {
    out[0] = ws[0] / fmaxf(ws[1], 1.f) * WEIGHT;
}

extern "C" void kernel_launch(void* const* d_in, const int* in_sizes, int n_in,
                              void* d_out, int out_size, void* d_ws, size_t ws_size,
                              hipStream_t stream) {
    const float* features = (const float*)d_in[0];
    const int* labels     = (const int*)d_in[1];
    const int* nbr        = (const int*)d_in[2];
    float* out = (float*)d_out;
    float* ws  = (float*)d_ws;

    hipMemsetAsync(ws, 0, 16, stream);   // ws[0]=loss, ws[1]=cnt, ws[2]=ctr

    if (ws_size >= WS_NEEDED) {
        unsigned char* tblA = (unsigned char*)d_ws + TBLA_OFF;
        unsigned char* tblB = (unsigned char*)d_ws + TBLB_OFF;
        unsigned short* d2A = (unsigned short*)((char*)d_ws + D2A_OFF);
        unsigned short* d2B = (unsigned short*)((char*)d_ws + D2B_OFF);
        int* ctr = (int*)d_ws + 2;

        to_fp8_split<<<CONVBLK, 256, 0, stream>>>(features, tblA, tblB);
        partial_d2<<<PART_BLOCKS, 256, 0, stream>>>(tblA, tblB, nbr, d2A, d2B);
        softmax_fin<<<SM_BLOCKS, 256, 0, stream>>>(d2A, d2B, labels, nbr, ws,
                                                   ctr, out, SM_BLOCKS);
    } else {
        contrast_fp32<<<NPTS / 16, 256, 0, stream>>>(features, labels, nbr, ws);
        contrast_finalize<<<1, 1, 0, stream>>>(ws, out);
    }
}

// Round 9
// 137.171 us; speedup vs baseline: 4.2793x; 4.2793x over previous
//
#include <hip/hip_runtime.h>
#include <math.h>
#include <string.h>

#define NPTS 200000
#define KNBR 16
#define CDIM 32
#define NITEM (NPTS * KNBR)               // 3,200,000
#define TEMP 0.1f
#define WEIGHT 0.1f
#define EPSV 1e-8f

#define PART_BLOCKS 2048                  // 1024 per dim-group
#define CHUNK (NITEM / 1024)              // 3125 items per partial block
#define CONVBLK (NPTS * CDIM / 8 / 256)   // 3125

#define SMP_BLOCKS 625
#define SMP_STRIDE (SMP_BLOCKS * 256)     // 160000 (multiple of 16)
#define SMP_ITER (NITEM / SMP_STRIDE)     // 20

// ---- workspace layout (256-aligned) ----
#define TBLA_OFF 256
#define TBLB_OFF (TBLA_OFF + NPTS * 16)           // 3,200,256
#define D2A_OFF  (TBLB_OFF + NPTS * 16)           // 6,400,512
#define D2B_OFF  (D2A_OFF + NITEM * 2)            // 12,800,512
#define BL_OFF   (D2B_OFF + NITEM * 2)            // 19,200,512
#define BC_OFF   (BL_OFF + SMP_BLOCKS * 4)        // +2500
#define WS_NEEDED ((size_t)(BC_OFF + SMP_BLOCKS * 4))

typedef float v2f __attribute__((ext_vector_type(2)));

static __device__ __forceinline__ unsigned short f32_to_f16b(float x) {
    _Float16 h = (_Float16)x;
    unsigned short u;
    __builtin_memcpy(&u, &h, 2);
    return u;
}
static __device__ __forceinline__ float f16b_to_f32(unsigned short u) {
    _Float16 h;
    __builtin_memcpy(&h, &u, 2);
    return (float)h;
}

// ---------- K1: f32 features -> two fp8 half-tables (16B rows each) --------
__global__ __launch_bounds__(256) void to_fp8_split(const float* __restrict__ f,
                                                    unsigned char* __restrict__ A,
                                                    unsigned char* __restrict__ B) {
    const int i = blockIdx.x * 256 + threadIdx.x;   // 800000 threads, 8 floats each
    const float4 a = ((const float4*)f)[2 * i];
    const float4 b = ((const float4*)f)[2 * i + 1];
    int w0 = 0, w1 = 0;
    w0 = __builtin_amdgcn_cvt_pk_fp8_f32(a.x, a.y, w0, false);
    w0 = __builtin_amdgcn_cvt_pk_fp8_f32(a.z, a.w, w0, true);
    w1 = __builtin_amdgcn_cvt_pk_fp8_f32(b.x, b.y, w1, false);
    w1 = __builtin_amdgcn_cvt_pk_fp8_f32(b.z, b.w, w1, true);
    const int fbase = i * 8;
    const int p = fbase >> 5;
    unsigned char* dst = ((fbase >> 4) & 1) ? B : A;
    *(uint2*)(dst + (size_t)p * 16 + (fbase & 15)) =
        make_uint2((unsigned)w0, (unsigned)w1);
}

// ---------- K2: per-item partial d^2 over 16 dims, XCD-grouped -------------
// (blockIdx&7)<4 -> XCDs 0-3 -> tblA (dims 0-15); else tblB (dims 16-31).
// Each XCD's random working set = 3.2MB half-table -> L2-resident -> hits.
__global__ __launch_bounds__(256) void partial_d2(
    const unsigned char* __restrict__ tblA,
    const unsigned char* __restrict__ tblB,
    const int* __restrict__ nbr,
    unsigned short* __restrict__ d2A,
    unsigned short* __restrict__ d2B) {
    const int b = blockIdx.x;
    const int grp = (b >> 2) & 1;
    const int r = (b >> 3) * 4 + (b & 3);
    const unsigned char* __restrict__ tbl = grp ? tblB : tblA;
    unsigned short* __restrict__ out = grp ? d2B : d2A;
    const int i0 = r * CHUNK;

    for (int t = threadIdx.x; t < CHUNK; t += 256) {
        const int i = i0 + t;
        const int idx = nbr[i];
        const int p = i >> 4;
        const uint4 nv = *(const uint4*)(tbl + (size_t)idx * 16);  // L2 hit
        const uint4 cv = *(const uint4*)(tbl + (size_t)p * 16);
        const unsigned* pn = (const unsigned*)&nv;
        const unsigned* pc = (const unsigned*)&cv;
        float d2 = 0.f;
        #pragma unroll
        for (int q = 0; q < 4; ++q) {
            v2f nl = __builtin_amdgcn_cvt_pk_f32_fp8((int)pn[q], false);
            v2f nh = __builtin_amdgcn_cvt_pk_f32_fp8((int)pn[q], true);
            v2f cl = __builtin_amdgcn_cvt_pk_f32_fp8((int)pc[q], false);
            v2f ch = __builtin_amdgcn_cvt_pk_f32_fp8((int)pc[q], true);
            float a0 = cl.x - nl.x, a1 = cl.y - nl.y;
            float a2 = ch.x - nh.x, a3 = ch.y - nh.y;
            d2 += a0 * a0 + a1 * a1 + a2 * a2 + a3 * a3;
        }
        out[i] = f32_to_f16b(d2);
    }
}

// ---------- K3: combine halves + softmax/mask; per-block plain stores ------
// 625 blocks x 256 threads x 20 items, stride 160000 (mult of 16 keeps each
// point's 16 items on 16 aligned lanes). NO device atomics, NO fences.
__global__ __launch_bounds__(256) void softmax_part(
    const unsigned short* __restrict__ d2A,
    const unsigned short* __restrict__ d2B,
    const int* __restrict__ labels,
    const int* __restrict__ nbr,
    float* __restrict__ bl, float* __restrict__ bc) {
    const int tid = threadIdx.x;
    const int lane = tid & 63;
    float loss_acc = 0.f, valid_acc = 0.f;

    for (int k = 0; k < SMP_ITER; ++k) {
        const int i = blockIdx.x * 256 + tid + k * SMP_STRIDE;
        const int idx = nbr[i];                    // coalesced
        const int p = i >> 4;
        const int labn = labels[idx];              // random, 800KB L2-resident
        const int labc = labels[p];                // broadcast over 16 lanes
        const float d2 = f16b_to_f32(d2A[i]) + f16b_to_f32(d2B[i]);
        const float d = sqrtf(d2 + EPSV);

        float mn = d;
        mn = fminf(mn, __shfl_xor(mn, 1));
        mn = fminf(mn, __shfl_xor(mn, 2));
        mn = fminf(mn, __shfl_xor(mn, 4));
        mn = fminf(mn, __shfl_xor(mn, 8));
        const float e = expf((mn - d) * (1.0f / TEMP));
        const bool pos = (labn == labc);

        float pos_s = pos ? e : 0.f;
        float neg_s = e;
        float cnt_s = pos ? 1.f : 0.f;
        #pragma unroll
        for (int off = 1; off <= 8; off <<= 1) {
            pos_s += __shfl_xor(pos_s, off);
            neg_s += __shfl_xor(neg_s, off);
            cnt_s += __shfl_xor(cnt_s, off);
        }
        if ((lane & 15) == 0) {
            const int icnt = (int)(cnt_s + 0.5f);
            if (icnt > 0 && icnt < KNBR) {
                loss_acc += -logf(pos_s / neg_s + EPSV);
                valid_acc += 1.f;
            }
        }
    }

    // lanes 0,16,32,48 hold data; fold across the wave
    loss_acc += __shfl_xor(loss_acc, 16);
    valid_acc += __shfl_xor(valid_acc, 16);
    loss_acc += __shfl_xor(loss_acc, 32);
    valid_acc += __shfl_xor(valid_acc, 32);

    __shared__ float sl[4], sv[4];
    if (lane == 0) { sl[tid >> 6] = loss_acc; sv[tid >> 6] = valid_acc; }
    __syncthreads();
    if (tid == 0) {
        bl[blockIdx.x] = sl[0] + sl[1] + sl[2] + sl[3];   // plain store
        bc[blockIdx.x] = sv[0] + sv[1] + sv[2] + sv[3];
    }
}

// ---------- K4: single-block final reduction (launch-ordered coherence) ----
__global__ __launch_bounds__(256) void final_reduce(const float* __restrict__ bl,
                                                    const float* __restrict__ bc,
                                                    float* __restrict__ out) {
    const int tid = threadIdx.x;
    float l = 0.f, v = 0.f;
    for (int i = tid; i < SMP_BLOCKS; i += 256) { l += bl[i]; v += bc[i]; }
    #pragma unroll
    for (int off = 1; off <= 32; off <<= 1) {
        l += __shfl_xor(l, off);
        v += __shfl_xor(v, off);
    }
    __shared__ float sl[4], sv[4];
    if ((tid & 63) == 0) { sl[tid >> 6] = l; sv[tid >> 6] = v; }
    __syncthreads();
    if (tid == 0) {
        const float S = sl[0] + sl[1] + sl[2] + sl[3];
        const float C = sv[0] + sv[1] + sv[2] + sv[3];
        out[0] = S / fmaxf(C, 1.f) * WEIGHT;
    }
}

// ---------------- fp32 direct fallback (tiny ws) ---------------------------
__global__ __launch_bounds__(256) void contrast_fp32(
    const float* __restrict__ features,
    const int* __restrict__ labels,
    const int* __restrict__ nbr,
    float* __restrict__ ws) {
    const int lane = threadIdx.x & 63;
    const int wave = threadIdx.x >> 6;
    const int p0 = blockIdx.x * 16 + wave * 4;
    const int m = lane >> 3;
    const int c = lane & 7;
    const int idx_l = nbr[p0 * KNBR + lane];
    const int labn_l = labels[idx_l];
    const int labc_l = labels[p0 + (lane >> 4)];
    float4 cen[4];
    #pragma unroll
    for (int pt = 0; pt < 4; ++pt)
        cen[pt] = *(const float4*)(features + (size_t)(p0 + pt) * CDIM + c * 4);
    int ridx[8];
    #pragma unroll
    for (int j = 0; j < 8; ++j) ridx[j] = __shfl(idx_l, 8 * j + m);
    float4 v[8];
    #pragma unroll
    for (int j = 0; j < 8; ++j)
        v[j] = *(const float4*)(features + (size_t)ridx[j] * CDIM + c * 4);
    float dj[8];
    #pragma unroll
    for (int j = 0; j < 8; ++j) {
        float4 ce = cen[j >> 1];
        float dx = ce.x - v[j].x, dy = ce.y - v[j].y;
        float dz = ce.z - v[j].z, dw = ce.w - v[j].w;
        float d2 = dx * dx + dy * dy + dz * dz + dw * dw;
        d2 += __shfl_xor(d2, 1);
        d2 += __shfl_xor(d2, 2);
        d2 += __shfl_xor(d2, 4);
        dj[j] = sqrtf(d2 + EPSV);
    }
    float loss_acc = 0.f, valid_acc = 0.f;
    #pragma unroll
    for (int pt = 0; pt < 4; ++pt) {
        float a = dj[2 * pt], b = dj[2 * pt + 1];
        float mn = fminf(a, b);
        mn = fminf(mn, __shfl_xor(mn, 8));
        mn = fminf(mn, __shfl_xor(mn, 16));
        mn = fminf(mn, __shfl_xor(mn, 32));
        const float ea = expf((mn - a) / TEMP);
        const float eb = expf((mn - b) / TEMP);
        const int la = __shfl(labn_l, 16 * pt + m);
        const int lb = __shfl(labn_l, 16 * pt + 8 + m);
        const int lc = __shfl(labc_l, 16 * pt);
        float pos_s = (la == lc ? ea : 0.f) + (lb == lc ? eb : 0.f);
        float neg_s = ea + eb;
        float cnt_s = (la == lc ? 1.f : 0.f) + (lb == lc ? 1.f : 0.f);
        #pragma unroll
        for (int off = 8; off <= 32; off <<= 1) {
            pos_s += __shfl_xor(pos_s, off);
            neg_s += __shfl_xor(neg_s, off);
            cnt_s += __shfl_xor(cnt_s, off);
        }
        if (lane == pt) {
            const int icnt = (int)(cnt_s + 0.5f);
            if (icnt > 0 && icnt < KNBR) {
                loss_acc += -logf(pos_s / neg_s + EPSV);
                valid_acc += 1.f;
            }
        }
    }
    __shared__ float s_loss, s_cnt;
    if (threadIdx.x == 0) { s_loss = 0.f; s_cnt = 0.f; }
    __syncthreads();
    if (lane < 4) { atomicAdd(&s_loss, loss_acc); atomicAdd(&s_cnt, valid_acc); }
    __syncthreads();
    if (threadIdx.x == 0) { atomicAdd(&ws[0], s_loss); atomicAdd(&ws[1], s_cnt); }
}

__global__ void contrast_finalize(const float* __restrict__ ws,
                                  float* __restrict__ out) {
    out[0] = ws[0] / fmaxf(ws[1], 1.f) * WEIGHT;
}

extern "C" void kernel_launch(void* const* d_in, const int* in_sizes, int n_in,
                              void* d_out, int out_size, void* d_ws, size_t ws_size,
                              hipStream_t stream) {
    const float* features = (const float*)d_in[0];
    const int* labels     = (const int*)d_in[1];
    const int* nbr        = (const int*)d_in[2];
    float* out = (float*)d_out;
    float* ws  = (float*)d_ws;

    if (ws_size >= WS_NEEDED) {
        unsigned char* tblA = (unsigned char*)d_ws + TBLA_OFF;
        unsigned char* tblB = (unsigned char*)d_ws + TBLB_OFF;
        unsigned short* d2A = (unsigned short*)((char*)d_ws + D2A_OFF);
        unsigned short* d2B = (unsigned short*)((char*)d_ws + D2B_OFF);
        float* bl = (float*)((char*)d_ws + BL_OFF);
        float* bc = (float*)((char*)d_ws + BC_OFF);

        to_fp8_split<<<CONVBLK, 256, 0, stream>>>(features, tblA, tblB);
        partial_d2<<<PART_BLOCKS, 256, 0, stream>>>(tblA, tblB, nbr, d2A, d2B);
        softmax_part<<<SMP_BLOCKS, 256, 0, stream>>>(d2A, d2B, labels, nbr, bl, bc);
        final_reduce<<<1, 256, 0, stream>>>(bl, bc, out);
    } else {
        hipMemsetAsync(ws, 0, 16, stream);
        contrast_fp32<<<NPTS / 16, 256, 0, stream>>>(features, labels, nbr, ws);
        contrast_finalize<<<1, 1, 0, stream>>>(ws, out);
    }
}